// Round 12
// baseline (191.539 us; speedup 1.0000x reference)
//
#include <hip/hip_runtime.h>
#include <hip/hip_bf16.h>
#include <stdint.h>

// Problem constants
#define B_M 512
#define D_K 512
#define C_N 100000
#define S_SCALE 64.0f
#define W_LOSS 0.003f
#define COS_M_C 0.79608379854905604f
#define SIN_M_C 0.60518640573603957f
#define THRESH_C (-0.79608379854905604f)
#define MM_C 0.39337116372842573f

typedef __bf16 bf16x8 __attribute__((ext_vector_type(8)));
typedef float f32x4 __attribute__((ext_vector_type(4)));

typedef const __attribute__((address_space(1))) unsigned char* gptr_t;
typedef __attribute__((address_space(3))) unsigned char* sptr_t;

__device__ __forceinline__ unsigned short f2bf(float f) {
  __bf16 h = (__bf16)f;
  return __builtin_bit_cast(unsigned short, h);
}

// ---------------------------------------------------------------------------
// Kernel 1: normalize emb rows (f32), write swizzled bf16 A-tiles to ws,
// compute target_logit[b] exactly in f32.
// wsA layout: 8 tiles (mhalf 0..1  x  ktile 0..3) of 64 KB;
// tile = [256 rows][256 B], byte-in-row XOR ((row&7)<<4)  (LDS image, BK=128).
// ---------------------------------------------------------------------------
__global__ __launch_bounds__(256) void prep_kernel(
    const float* __restrict__ emb, const float* __restrict__ Kg,
    const int* __restrict__ label, unsigned char* __restrict__ wsA,
    float* __restrict__ tl)
{
  int b = blockIdx.x, t = threadIdx.x;
  __shared__ float row[512];
  __shared__ float r1[256], r2[256];

  float2 v = ((const float2*)(emb + (size_t)b * 512))[t];
  r1[t] = v.x * v.x + v.y * v.y;
  __syncthreads();
  for (int s = 128; s > 0; s >>= 1) {
    if (t < s) r1[t] += r1[t + s];
    __syncthreads();
  }
  float inv = 1.0f / sqrtf(r1[0]);
  float e0 = v.x * inv, e1 = v.y * inv;
  row[2 * t] = e0;
  row[2 * t + 1] = e1;

  {
    int mhalf = b >> 8, lrow = b & 255;
    int kk = t >> 6;  // (2t)/128 : k-tile index (0..3)
    int byte_in = (4 * (t & 63)) ^ ((lrow & 7) << 4);
    ushort2 h;
    h.x = f2bf(e0);
    h.y = f2bf(e1);
    *(ushort2*)(wsA + (size_t)(mhalf * 4 + kk) * 65536 + lrow * 256 + byte_in) = h;
  }
  __syncthreads();

  int lab = label[b];
  const float* kc = Kg + lab;
  float dot = 0.f, csq = 0.f;
  for (int d = t; d < 512; d += 256) {
    float kv = kc[(size_t)d * C_N];
    dot += row[d] * kv;
    csq += kv * kv;
  }
  r1[t] = dot;
  r2[t] = csq;
  __syncthreads();
  for (int s = 128; s > 0; s >>= 1) {
    if (t < s) { r1[t] += r1[t + s]; r2[t] += r2[t + s]; }
    __syncthreads();
  }
  if (t == 0) {
    float tlv = r1[0] / sqrtf(r2[0]);
    tl[b] = fminf(1.f, fmaxf(-1.f, tlv));
  }
}

// ---------------------------------------------------------------------------
// Kernel 2: t_new, cos_theta_m[b], final_target_logit[b], center-loss scalar.
// ---------------------------------------------------------------------------
__global__ __launch_bounds__(512) void finalize_kernel(
    const float* __restrict__ tl, const float* __restrict__ t_in,
    float* __restrict__ ctm, float* __restrict__ ftl,
    float* __restrict__ tnew, float* __restrict__ out3)
{
  int t = threadIdx.x;
  float v = tl[t];
  __shared__ float r1[512], r2[512];
  float ac = acosf(v);
  r1[t] = v;
  r2[t] = ac * sqrtf(ac);  // acos^1.5
  __syncthreads();
  for (int s = 256; s > 0; s >>= 1) {
    if (t < s) { r1[t] += r1[t + s]; r2[t] += r2[t + s]; }
    __syncthreads();
  }
  if (t == 0) {
    tnew[0] = 0.99f * t_in[0] + 0.01f * (r1[0] / 512.0f);
    out3[0] = S_SCALE * W_LOSS * (r2[0] / 512.0f);
  }
  float st = sqrtf(fmaxf(0.f, 1.f - v * v));
  float cm = v * COS_M_C - st * SIN_M_C;
  ctm[t] = cm;
  ftl[t] = (v > THRESH_C) ? cm : (v - MM_C);
}

// ---------------------------------------------------------------------------
// Kernel 3: fused GEMM + epilogue. BK=128: 4 K-steps -> barrier pairs 16->8;
// 1-deep B prefetch now has a full doubled compute phase of flight (>= HBM
// latency) so no 2-deep register scheme needed. R7's proven sync skeleton:
// barrier -> stage A glls -> WRITE_B -> LOAD_B(next) -> counted vmcnt ->
// barrier -> compute. vmcnt(16) retires the 8 A-DMAs, keeps B[k+1] flying.
// BM=256, BN=64; 512 threads, 8 waves (2M x 4N), wave tile 128x16.
// LDS = A 64KB + B 16KB = 80KB exactly -> 2 blocks/CU.
// __launch_bounds__(512,2): spill-proof (R6/R8/R9 lesson, R10/R11 verified).
// Epilogue: single-pass 64KB stage (aliases A) -> 256B-contiguous NT stores.
// ---------------------------------------------------------------------------
#define LDS_TOTAL 81920  // A [0,65536); B [65536,81920)
// params alias B after loop: colpart @65536 (2048), invn @+2048 (256),
// ctm @+2304 (1024), ftl @+3328 (1024), lab @+4352 (1024)

__global__ __launch_bounds__(512, 2) void gemm_kernel(
    const float* __restrict__ Kg, const unsigned char* __restrict__ wsA,
    const float* __restrict__ ctm_g, const float* __restrict__ ftl_g,
    const int* __restrict__ label, const float* __restrict__ tnew_g,
    float* __restrict__ out1, float* __restrict__ out2)
{
  __shared__ __align__(16) unsigned char smem[LDS_TOTAL];

  int t = threadIdx.x;
  int lane = t & 63, wv = t >> 6;
  int wm = wv >> 2, wn = wv & 3;  // 2M x 4N
  int kq = lane >> 4, lr = lane & 15;

  // m204 bijective XCD swizzle: nwg=3126, q8=390, r8=6. mhalf pair (2p,2p+1)
  // contiguous on one XCD -> B panel L2 reuse across the pair.
  int bid = blockIdx.x;
  {
    int xcd = bid & 7, seq = bid >> 3;
    bid = (xcd < 6 ? xcd * 391 : 6 * 391 + (xcd - 6) * 390) + seq;
  }
  int pid = bid >> 1, mhalf = bid & 1;
  long c0 = (long)pid * 64;

  // B staging: thread owns column c (t&63), k-segment kseg (t>>6): 16 rows
  int c = t & 63, kseg = t >> 6;
  bool binb = (c0 + c) < C_N;
  const float* Bcol = Kg + c0 + c + (size_t)kseg * 16 * C_N;

  f32x4 acc[8] = {};
  float csq = 0.f;
  float bf[16];

  const unsigned char* wsTile = wsA + (size_t)mhalf * (4 * 65536);
  unsigned char* smemA = smem;
  unsigned char* smemB = smem + 65536;
  unsigned char* browB = smemB + c * 256;

#define LOAD_B(j)                                                            \
  {                                                                          \
    const float* src = Bcol + (size_t)((j) * 128) * C_N;                     \
    _Pragma("unroll") for (int i = 0; i < 16; ++i)                           \
        bf[i] = binb ? src[(size_t)i * C_N] : 0.f;                           \
  }

#define WRITE_B()                                                            \
  {                                                                          \
    _Pragma("unroll") for (int i = 0; i < 16; ++i) csq += bf[i] * bf[i];     \
    union { unsigned short u[16]; uint4 q[2]; } pk;                          \
    _Pragma("unroll") for (int i = 0; i < 16; ++i) pk.u[i] = f2bf(bf[i]);    \
    _Pragma("unroll") for (int h = 0; h < 2; ++h)                            \
      *(uint4*)(browB + ((kseg * 32 + h * 16) ^ ((c & 7) << 4))) = pk.q[h];  \
  }

  LOAD_B(0);

  // ---- main loop: 4 K-steps (K=128 each), R7 discipline.
#pragma unroll
  for (int kkt = 0; kkt < 4; ++kkt) {
    __syncthreads();  // BARRIER-A: prior compute's LDS reads complete
    // stage A[kkt]: 8 gll per thread (64KB tile), L2-resident source
    const unsigned char* tA = wsTile + (size_t)kkt * 65536;
#pragma unroll
    for (int i = 0; i < 8; ++i) {
      int off = wv * 8192 + i * 1024;
      __builtin_amdgcn_global_load_lds((gptr_t)(tA + off + lane * 16),
                                       (sptr_t)(smemA + off), 16, 0, 0);
    }
    __builtin_amdgcn_sched_barrier(0);
    WRITE_B();  // B[kkt] regs -> LDS (compiler waits those; A glls newer)
    if (kkt < 3) LOAD_B(kkt + 1);  // 16 loads in flight across the barrier
    __builtin_amdgcn_sched_barrier(0);
    // retire the 8 A-DMAs (oldest); keep B[kkt+1] (16 newest) outstanding
    if (kkt < 3) {
      asm volatile("s_waitcnt vmcnt(16)" ::: "memory");
    } else {
      asm volatile("s_waitcnt vmcnt(0)" ::: "memory");
    }
    __builtin_amdgcn_sched_barrier(0);
    __syncthreads();  // BARRIER-B: A[kkt] landed, B[kkt] visible

#pragma unroll
    for (int ks = 0; ks < 4; ++ks) {
      int kb = ks * 64 + kq * 16;
      int n = wn * 16 + lr;
      bf16x8 bfr = *(const bf16x8*)(smemB + n * 256 + (kb ^ ((n & 7) << 4)));
#pragma unroll
      for (int mf = 0; mf < 8; ++mf) {
        int m = wm * 128 + mf * 16 + lr;
        bf16x8 afr = *(const bf16x8*)(smemA + m * 256 + (kb ^ ((m & 7) << 4)));
        acc[mf] = __builtin_amdgcn_mfma_f32_16x16x32_bf16(afr, bfr, acc[mf], 0, 0, 0);
      }
    }
  }

  __syncthreads();  // all compute LDS reads done (A and B now reusable)

  // ---- params (alias B region) + single-pass acc stage (aliases A region)
  float* colpart = (float*)(smemB);          // [8][64]
  float* invn    = (float*)(smemB + 2048);   // [64]
  float* ctm_s   = (float*)(smemB + 2304);   // [256]
  float* ftl_s   = (float*)(smemB + 3328);   // [256]
  int*   lab_s   = (int*)  (smemB + 4352);   // [256]
  colpart[t] = csq;
  if (t < 256) {
    ctm_s[t] = ctm_g[mhalf * 256 + t];
    ftl_s[t] = ftl_g[mhalf * 256 + t];
    lab_s[t] = label[mhalf * 256 + t];
  }
  // stage the whole 256x64 f32 tile into [0,65536)
#pragma unroll
  for (int mf = 0; mf < 8; ++mf) {
#pragma unroll
    for (int j = 0; j < 4; ++j) {
      int row = wm * 128 + mf * 16 + kq * 4 + j;  // [0,256)
      int col = wn * 16 + lr;                     // [0,64)
      *(float*)(smem + row * 256 + ((col * 4) ^ (((row >> 2) & 3) << 6))) =
          acc[mf][j];
    }
  }
  __syncthreads();
  if (t < 64) {
    float s = 0.f;
#pragma unroll
    for (int g = 0; g < 8; ++g) s += colpart[g * 64 + t];
    invn[t] = 1.0f / sqrtf(fmaxf(s, 1e-30f));
  }
  __syncthreads();
  float tn = tnew_g[0];

  // ---- stream out: 8 iterations, 256B-contiguous rows, NT stores
#pragma unroll
  for (int rr = 0; rr < 8; ++rr) {
    int row = rr * 32 + (t >> 4);   // [0,256)
    int cb = (t & 15) * 4;          // col base [0,64)
    f32x4 v = *(const f32x4*)(smem + row * 256 + ((cb * 4) ^ (((row >> 2) & 3) << 6)));
    long cgs = c0 + cb;
    if (cgs < C_N) {  // group fully valid (C_N % 4 == 0)
      float cm = ctm_s[row], fl = ftl_s[row];
      int lb = lab_s[row];
      f32x4 iv = *(const f32x4*)(invn + cb);
      f32x4 o1v, o2v;
#pragma unroll
      for (int jj = 0; jj < 4; ++jj) {
        float cosv = fminf(1.f, fmaxf(-1.f, v[jj] * iv[jj]));
        o2v[jj] = cosv * S_SCALE;
        float ct = (cosv > cm) ? cosv * (tn + cosv) : cosv;
        if (lb == (int)(cgs + jj)) ct = fl;
        o1v[jj] = ct * S_SCALE;
      }
      size_t idx = (size_t)(mhalf * 256 + row) * C_N + cgs;
      __builtin_nontemporal_store(o1v, (f32x4*)(out1 + idx));
      __builtin_nontemporal_store(o2v, (f32x4*)(out2 + idx));
    }
  }
#undef LOAD_B
#undef WRITE_B
}

// ---------------------------------------------------------------------------
extern "C" void kernel_launch(void* const* d_in, const int* in_sizes, int n_in,
                              void* d_out, int out_size, void* d_ws, size_t ws_size,
                              hipStream_t stream)
{
  const float* emb   = (const float*)d_in[0];
  const float* Kg    = (const float*)d_in[1];
  const float* t_in  = (const float*)d_in[2];
  const int*   label = (const int*)d_in[3];

  float* out1 = (float*)d_out;                 // output * S   [512*100000]
  float* out2 = out1 + (size_t)B_M * C_N;      // origin * S   [512*100000]
  float* out3 = out1 + 2 * (size_t)B_M * C_N;  // scalar loss

  unsigned char* wsA = (unsigned char*)d_ws;   // 512KB swizzled bf16 A tiles
  float* tl   = (float*)((unsigned char*)d_ws + 524288);
  float* ctm  = tl + 512;
  float* ftl  = ctm + 512;
  float* tnew = ftl + 512;

  prep_kernel<<<512, 256, 0, stream>>>(emb, Kg, label, wsA, tl);
  finalize_kernel<<<1, 512, 0, stream>>>(tl, t_in, ctm, ftl, tnew, out3);
  int nb = 2 * 1563;  // BN=64 -> 1563 pids x 2 mhalf = 3126
  gemm_kernel<<<nb, 512, 0, stream>>>(Kg, wsA, ctm, ftl, label, tnew, out1, out2);
}

// Round 13
// 144.406 us; speedup vs baseline: 1.3264x; 1.3264x over previous
//
#include <hip/hip_runtime.h>
#include <hip/hip_bf16.h>
#include <stdint.h>

// Problem constants
#define B_M 512
#define D_K 512
#define C_N 100000
#define S_SCALE 64.0f
#define W_LOSS 0.003f
#define COS_M_C 0.79608379854905604f
#define SIN_M_C 0.60518640573603957f
#define THRESH_C (-0.79608379854905604f)
#define MM_C 0.39337116372842573f

typedef __bf16 bf16x8 __attribute__((ext_vector_type(8)));
typedef float f32x4 __attribute__((ext_vector_type(4)));

typedef const __attribute__((address_space(1))) unsigned char* gptr_t;
typedef __attribute__((address_space(3))) unsigned char* sptr_t;

__device__ __forceinline__ unsigned short f2bf(float f) {
  __bf16 h = (__bf16)f;
  return __builtin_bit_cast(unsigned short, h);
}

// ---------------------------------------------------------------------------
// Kernel 1: normalize emb rows (f32), write swizzled bf16 A-tiles to ws,
// compute target_logit[b] exactly in f32.
// wsA layout: 16 tiles (mhalf 0..1  x  ktile 0..7) of 32 KB;
// tile = [256 rows][128 B], byte-in-row XOR ((row&7)<<4)  (LDS image).
// ---------------------------------------------------------------------------
__global__ __launch_bounds__(256) void prep_kernel(
    const float* __restrict__ emb, const float* __restrict__ Kg,
    const int* __restrict__ label, unsigned char* __restrict__ wsA,
    float* __restrict__ tl)
{
  int b = blockIdx.x, t = threadIdx.x;
  __shared__ float row[512];
  __shared__ float r1[256], r2[256];

  float2 v = ((const float2*)(emb + (size_t)b * 512))[t];
  r1[t] = v.x * v.x + v.y * v.y;
  __syncthreads();
  for (int s = 128; s > 0; s >>= 1) {
    if (t < s) r1[t] += r1[t + s];
    __syncthreads();
  }
  float inv = 1.0f / sqrtf(r1[0]);
  float e0 = v.x * inv, e1 = v.y * inv;
  row[2 * t] = e0;
  row[2 * t + 1] = e1;

  {
    int mhalf = b >> 8, lrow = b & 255;
    int kk = t >> 5;  // (2t)/64 : k-tile index
    int byte_in = (4 * (t & 31)) ^ ((lrow & 7) << 4);
    ushort2 h;
    h.x = f2bf(e0);
    h.y = f2bf(e1);
    *(ushort2*)(wsA + (size_t)(mhalf * 8 + kk) * 32768 + lrow * 128 + byte_in) = h;
  }
  __syncthreads();

  int lab = label[b];
  const float* kc = Kg + lab;
  float dot = 0.f, csq = 0.f;
  for (int d = t; d < 512; d += 256) {
    float kv = kc[(size_t)d * C_N];
    dot += row[d] * kv;
    csq += kv * kv;
  }
  r1[t] = dot;
  r2[t] = csq;
  __syncthreads();
  for (int s = 128; s > 0; s >>= 1) {
    if (t < s) { r1[t] += r1[t + s]; r2[t] += r2[t + s]; }
    __syncthreads();
  }
  if (t == 0) {
    float tlv = r1[0] / sqrtf(r2[0]);
    tl[b] = fminf(1.f, fmaxf(-1.f, tlv));
  }
}

// ---------------------------------------------------------------------------
// Kernel 2: fused GEMM + epilogue (finalize folded in; R5-proven pattern).
// R11's deep pipeline at the BM=256/BN=64 tile — main loop untouched:
// A double-buffered LDS (2x32KB), gll prefetch 1 ahead; B 2 steps ahead in
// register sets bf0/bf1; per-step vmcnt(8) retires {B[k+1], A[k+1] DMA},
// keeps B[k+2] in flight. __launch_bounds__(512,2): spill-proof.
// Epilogue: per-block recompute of tnew/ctm/ftl from tl[] (L2-hot, in-LDS
// 512-reduction); block 0 writes the scalar loss. Then acc -> LDS ->
// 256B-contiguous NT stores. Saves the 1-block finalize launch.
// ---------------------------------------------------------------------------
#define LDS_TOTAL 73728  // A dbuf [0,65536); B [65536,73728)

__global__ __launch_bounds__(512, 2) void gemm_kernel(
    const float* __restrict__ Kg, const unsigned char* __restrict__ wsA,
    const float* __restrict__ tl_g, const float* __restrict__ t_in_g,
    const int* __restrict__ label,
    float* __restrict__ out1, float* __restrict__ out2,
    float* __restrict__ out3)
{
  __shared__ __align__(16) unsigned char smem[LDS_TOTAL];

  int t = threadIdx.x;
  int lane = t & 63, wv = t >> 6;
  int wm = wv >> 2, wn = wv & 3;  // 2M x 4N
  int kq = lane >> 4, lr = lane & 15;
  bool orig0 = (blockIdx.x == 0);

  // m204 bijective XCD swizzle: nwg=3126, q8=390, r8=6. mhalf pair (2p,2p+1)
  // contiguous on one XCD -> B panel L2 reuse across the pair.
  int bid = blockIdx.x;
  {
    int xcd = bid & 7, seq = bid >> 3;
    bid = (xcd < 6 ? xcd * 391 : 6 * 391 + (xcd - 6) * 390) + seq;
  }
  int pid = bid >> 1, mhalf = bid & 1;
  long c0 = (long)pid * 64;

  // B staging: thread owns column c (t&63), k-segment kseg (t>>6): 8 rows
  int c = t & 63, kseg = t >> 6;
  bool binb = (c0 + c) < C_N;
  const float* Bcol = Kg + c0 + c + (size_t)kseg * 8 * C_N;

  f32x4 acc[8] = {};
  float csq = 0.f;
  float bf0[8], bf1[8];  // B[j] lives in set (j&1)

  const unsigned char* wsTile = wsA + (size_t)mhalf * (8 * 32768);
  unsigned char* smemB = smem + 65536;
  unsigned char* browB = smemB + c * 128;

#define LOAD_B(dst, j)                                                       \
  {                                                                          \
    const float* src = Bcol + (size_t)((j) * 64) * C_N;                      \
    _Pragma("unroll") for (int i = 0; i < 8; ++i)                            \
        dst[i] = binb ? src[(size_t)i * C_N] : 0.f;                          \
  }

#define WRITE_B(src)                                                         \
  {                                                                          \
    _Pragma("unroll") for (int i = 0; i < 8; ++i) csq += src[i] * src[i];    \
    union { unsigned short u[8]; uint4 q; } pk;                              \
    _Pragma("unroll") for (int i = 0; i < 8; ++i) pk.u[i] = f2bf(src[i]);    \
    *(uint4*)(browB + ((kseg * 16) ^ ((c & 7) << 4))) = pk.q;                \
  }

  // ---- prologue: A[0] DMA -> buf0, B[0]/B[1] reg loads, B[0] -> LDS
  {
#pragma unroll
    for (int i = 0; i < 4; ++i) {
      int off = wv * 4096 + i * 1024;
      __builtin_amdgcn_global_load_lds((gptr_t)(wsTile + off + lane * 16),
                                       (sptr_t)(smem + off), 16, 0, 0);
    }
    __builtin_amdgcn_sched_barrier(0);
    LOAD_B(bf0, 0);
    __builtin_amdgcn_sched_barrier(0);
    LOAD_B(bf1, 1);
    __builtin_amdgcn_sched_barrier(0);
    asm volatile("s_waitcnt vmcnt(8)" ::: "memory");  // A[0]+B[0] done
    __builtin_amdgcn_sched_barrier(0);
    WRITE_B(bf0);
    __syncthreads();
  }

  // ---- main loop: 8 K-steps, fully unrolled (static reg-set selects)
#pragma unroll
  for (int kkt = 0; kkt < 8; ++kkt) {
    int cur = kkt & 1;
    if (kkt < 7) {
      // prefetch A[kkt+1] into the other buffer (DMA overlaps compute)
      const unsigned char* tA = wsTile + (size_t)(kkt + 1) * 32768;
#pragma unroll
      for (int i = 0; i < 4; ++i) {
        int off = wv * 4096 + i * 1024;
        __builtin_amdgcn_global_load_lds((gptr_t)(tA + off + lane * 16),
                                         (sptr_t)(smem + (cur ^ 1) * 32768 + off), 16, 0, 0);
      }
      __builtin_amdgcn_sched_barrier(0);
    }
    if (kkt < 6) {
      if (kkt & 1) { LOAD_B(bf1, kkt + 2); } else { LOAD_B(bf0, kkt + 2); }
      __builtin_amdgcn_sched_barrier(0);
    }

    // compute current buffers
    const unsigned char* Ab = smem + cur * 32768;
#pragma unroll
    for (int ks = 0; ks < 2; ++ks) {
      int kb = ks * 64 + kq * 16;
      int n = wn * 16 + lr;
      bf16x8 bfr = *(const bf16x8*)(smemB + n * 128 + (kb ^ ((n & 7) << 4)));
#pragma unroll
      for (int mf = 0; mf < 8; ++mf) {
        int m = wm * 128 + mf * 16 + lr;
        bf16x8 afr = *(const bf16x8*)(Ab + m * 128 + (kb ^ ((m & 7) << 4)));
        acc[mf] = __builtin_amdgcn_mfma_f32_16x16x32_bf16(afr, bfr, acc[mf], 0, 0, 0);
      }
    }

    // counted wait: retire {B[kkt+1] regs (8), A[kkt+1] DMA (4)}, keep
    // B[kkt+2] (8 newest) in flight across the barrier. Tail drains fully.
    if (kkt < 6) {
      asm volatile("s_waitcnt vmcnt(8)" ::: "memory");
    } else {
      asm volatile("s_waitcnt vmcnt(0)" ::: "memory");
    }
    __builtin_amdgcn_sched_barrier(0);
    __syncthreads();  // barrier-1: B-LDS reads done, A[kkt+1] landed

    if (kkt < 7) {
      if (kkt & 1) { WRITE_B(bf0); } else { WRITE_B(bf1); }
      __syncthreads();  // barrier-2: B[kkt+1] visible
    }
  }

  // ---- finalize fold + column norms.
  // B region (dead): colpart @+0 (2048), invn @+2048 (256), ctm @+2304
  // (1024), ftl @+3328 (1024), lab @+4352 (1024) -> 5376 < 8192.
  // A region (dead; epilogue staging uses [0,32768)): red1 @40960, red2 @43008.
  float* colpart = (float*)(smemB);          // [8][64]
  float* invn    = (float*)(smemB + 2048);   // [64]
  float* ctm_s   = (float*)(smemB + 2304);   // [256]
  float* ftl_s   = (float*)(smemB + 3328);   // [256]
  int*   lab_s   = (int*)  (smemB + 4352);   // [256]
  float* red1    = (float*)(smem + 40960);   // [512]
  float* red2    = (float*)(smem + 43008);   // [512]

  colpart[t] = csq;
  {
    float tlv = tl_g[t];
    float ac = acosf(tlv);
    red1[t] = tlv;
    red2[t] = ac * sqrtf(ac);  // acos^1.5
  }
  if (t < 256) {
    lab_s[t] = label[mhalf * 256 + t];
  } else {
    int r = t - 256;
    float v2 = tl_g[mhalf * 256 + r];
    float st = sqrtf(fmaxf(0.f, 1.f - v2 * v2));
    float cm = v2 * COS_M_C - st * SIN_M_C;
    ctm_s[r] = cm;
    ftl_s[r] = (v2 > THRESH_C) ? cm : (v2 - MM_C);
  }
  __syncthreads();
  if (t < 64) {
    float s = 0.f;
#pragma unroll
    for (int g = 0; g < 8; ++g) s += colpart[g * 64 + t];
    invn[t] = 1.0f / sqrtf(fmaxf(s, 1e-30f));
  }
  for (int s = 256; s > 0; s >>= 1) {
    __syncthreads();
    if (t < s) { red1[t] += red1[t + s]; red2[t] += red2[t + s]; }
  }
  __syncthreads();
  float tn = 0.99f * t_in_g[0] + 0.01f * (red1[0] * (1.0f / 512.0f));
  if (orig0 && t == 0) out3[0] = S_SCALE * W_LOSS * (red2[0] * (1.0f / 512.0f));
  __syncthreads();

  // ---- epilogue: 2 chunks of 128 rows; stage acc in LDS (aliases Abuf,
  // barrier-separated from last compute), 256B-contiguous NT stores.
  for (int q = 0; q < 2; ++q) {
    if (wm == q) {
#pragma unroll
      for (int mf = 0; mf < 8; ++mf) {
#pragma unroll
        for (int j = 0; j < 4; ++j) {
          int row = mf * 16 + kq * 4 + j;  // [0,128)
          int col = wn * 16 + lr;          // [0,64)
          *(float*)(smem + row * 256 + ((col * 4) ^ (((row >> 2) & 3) << 6))) =
              acc[mf][j];
        }
      }
    }
    __syncthreads();
#pragma unroll
    for (int rr = 0; rr < 4; ++rr) {
      int row = rr * 32 + (t >> 4);   // [0,128)
      int cb = (t & 15) * 4;          // col base [0,64)
      f32x4 v = *(const f32x4*)(smem + row * 256 + ((cb * 4) ^ (((row >> 2) & 3) << 6)));
      long cgs = c0 + cb;
      if (cgs < C_N) {  // group fully valid (C_N % 4 == 0)
        int lrow = q * 128 + row;
        float cm = ctm_s[lrow], fl = ftl_s[lrow];
        int lb = lab_s[lrow];
        f32x4 iv = *(const f32x4*)(invn + cb);
        f32x4 o1v, o2v;
#pragma unroll
        for (int jj = 0; jj < 4; ++jj) {
          float cosv = fminf(1.f, fmaxf(-1.f, v[jj] * iv[jj]));
          o2v[jj] = cosv * S_SCALE;
          float ct = (cosv > cm) ? cosv * (tn + cosv) : cosv;
          if (lb == (int)(cgs + jj)) ct = fl;
          o1v[jj] = ct * S_SCALE;
        }
        size_t idx = (size_t)(mhalf * 256 + lrow) * C_N + cgs;
        __builtin_nontemporal_store(o1v, (f32x4*)(out1 + idx));
        __builtin_nontemporal_store(o2v, (f32x4*)(out2 + idx));
      }
    }
    __syncthreads();
  }
#undef LOAD_B
#undef WRITE_B
}

// ---------------------------------------------------------------------------
extern "C" void kernel_launch(void* const* d_in, const int* in_sizes, int n_in,
                              void* d_out, int out_size, void* d_ws, size_t ws_size,
                              hipStream_t stream)
{
  const float* emb   = (const float*)d_in[0];
  const float* Kg    = (const float*)d_in[1];
  const float* t_in  = (const float*)d_in[2];
  const int*   label = (const int*)d_in[3];

  float* out1 = (float*)d_out;                 // output * S   [512*100000]
  float* out2 = out1 + (size_t)B_M * C_N;      // origin * S   [512*100000]
  float* out3 = out1 + 2 * (size_t)B_M * C_N;  // scalar loss

  unsigned char* wsA = (unsigned char*)d_ws;   // 512KB swizzled bf16 A tiles
  float* tl = (float*)((unsigned char*)d_ws + 524288);

  prep_kernel<<<512, 256, 0, stream>>>(emb, Kg, label, wsA, tl);
  int nb = 2 * 1563;  // BN=64 -> 1563 pids x 2 mhalf = 3126
  gemm_kernel<<<nb, 512, 0, stream>>>(Kg, wsA, tl, t_in, label,
                                      out1, out2, out3);
}

// Round 14
// 143.528 us; speedup vs baseline: 1.3345x; 1.0061x over previous
//
#include <hip/hip_runtime.h>
#include <hip/hip_bf16.h>
#include <stdint.h>

// Problem constants
#define B_M 512
#define D_K 512
#define C_N 100000
#define S_SCALE 64.0f
#define W_LOSS 0.003f
#define COS_M_C 0.79608379854905604f
#define SIN_M_C 0.60518640573603957f
#define THRESH_C (-0.79608379854905604f)
#define MM_C 0.39337116372842573f

typedef __bf16 bf16x8 __attribute__((ext_vector_type(8)));
typedef float f32x4 __attribute__((ext_vector_type(4)));

typedef const __attribute__((address_space(1))) unsigned char* gptr_t;
typedef __attribute__((address_space(3))) unsigned char* sptr_t;

__device__ __forceinline__ unsigned short f2bf(float f) {
  __bf16 h = (__bf16)f;
  return __builtin_bit_cast(unsigned short, h);
}

// ---------------------------------------------------------------------------
// Kernel 1: normalize emb rows (f32), write swizzled bf16 A-tiles to ws,
// compute target_logit[b] exactly in f32.
// wsA layout: 16 tiles (mhalf 0..1  x  ktile 0..7) of 32 KB;
// tile = [256 rows][128 B], byte-in-row XOR ((row&7)<<4)  (LDS image).
// ---------------------------------------------------------------------------
__global__ __launch_bounds__(256) void prep_kernel(
    const float* __restrict__ emb, const float* __restrict__ Kg,
    const int* __restrict__ label, unsigned char* __restrict__ wsA,
    float* __restrict__ tl)
{
  int b = blockIdx.x, t = threadIdx.x;
  __shared__ float row[512];
  __shared__ float r1[256], r2[256];

  float2 v = ((const float2*)(emb + (size_t)b * 512))[t];
  r1[t] = v.x * v.x + v.y * v.y;
  __syncthreads();
  for (int s = 128; s > 0; s >>= 1) {
    if (t < s) r1[t] += r1[t + s];
    __syncthreads();
  }
  float inv = 1.0f / sqrtf(r1[0]);
  float e0 = v.x * inv, e1 = v.y * inv;
  row[2 * t] = e0;
  row[2 * t + 1] = e1;

  {
    int mhalf = b >> 8, lrow = b & 255;
    int kk = t >> 5;  // (2t)/64 : k-tile index
    int byte_in = (4 * (t & 31)) ^ ((lrow & 7) << 4);
    ushort2 h;
    h.x = f2bf(e0);
    h.y = f2bf(e1);
    *(ushort2*)(wsA + (size_t)(mhalf * 8 + kk) * 32768 + lrow * 128 + byte_in) = h;
  }
  __syncthreads();

  int lab = label[b];
  const float* kc = Kg + lab;
  float dot = 0.f, csq = 0.f;
  for (int d = t; d < 512; d += 256) {
    float kv = kc[(size_t)d * C_N];
    dot += row[d] * kv;
    csq += kv * kv;
  }
  r1[t] = dot;
  r2[t] = csq;
  __syncthreads();
  for (int s = 128; s > 0; s >>= 1) {
    if (t < s) { r1[t] += r1[t + s]; r2[t] += r2[t + s]; }
    __syncthreads();
  }
  if (t == 0) {
    float tlv = r1[0] / sqrtf(r2[0]);
    tl[b] = fminf(1.f, fmaxf(-1.f, tlv));
  }
}

// ---------------------------------------------------------------------------
// Kernel 2: t_new, cos_theta_m[b], final_target_logit[b], center-loss scalar.
// ---------------------------------------------------------------------------
__global__ __launch_bounds__(512) void finalize_kernel(
    const float* __restrict__ tl, const float* __restrict__ t_in,
    float* __restrict__ ctm, float* __restrict__ ftl,
    float* __restrict__ tnew, float* __restrict__ out3)
{
  int t = threadIdx.x;
  float v = tl[t];
  __shared__ float r1[512], r2[512];
  float ac = acosf(v);
  r1[t] = v;
  r2[t] = ac * sqrtf(ac);  // acos^1.5
  __syncthreads();
  for (int s = 256; s > 0; s >>= 1) {
    if (t < s) { r1[t] += r1[t + s]; r2[t] += r2[t + s]; }
    __syncthreads();
  }
  if (t == 0) {
    tnew[0] = 0.99f * t_in[0] + 0.01f * (r1[0] / 512.0f);
    out3[0] = S_SCALE * W_LOSS * (r2[0] / 512.0f);
  }
  float st = sqrtf(fmaxf(0.f, 1.f - v * v));
  float cm = v * COS_M_C - st * SIN_M_C;
  ctm[t] = cm;
  ftl[t] = (v > THRESH_C) ? cm : (v - MM_C);
}

// ---------------------------------------------------------------------------
// Kernel 3: fused GEMM + epilogue. R4's deep pipeline at R7's winning tile.
// BM=256, BN=64, BK=64; 512 threads, 8 waves (2M x 4N), wave tile 128x16.
// A double-buffered LDS (2x32KB), gll prefetch 1 step ahead (L2-resident ws).
// B prefetched 2 steps ahead into register sets bf0/bf1 (B[j] in set j&1);
// per-step counted vmcnt(8) retires {B[k+1] regs, A[k+1] DMA} and keeps
// B[k+2] (8 newest) in flight -> B flight ~2 compute phases >= HBM latency.
// __launch_bounds__(512,2): spill-proof (R6/R8/R9 lesson, R10 verified).
// Epilogue: acc -> LDS (f32, XOR-swizzled) -> 256B-contiguous NT stores.
// ---------------------------------------------------------------------------
#define LDS_TOTAL 73728  // A dbuf [0,65536); B [65536,73728)

__global__ __launch_bounds__(512, 2) void gemm_kernel(
    const float* __restrict__ Kg, const unsigned char* __restrict__ wsA,
    const float* __restrict__ ctm_g, const float* __restrict__ ftl_g,
    const int* __restrict__ label, const float* __restrict__ tnew_g,
    float* __restrict__ out1, float* __restrict__ out2)
{
  __shared__ __align__(16) unsigned char smem[LDS_TOTAL];

  int t = threadIdx.x;
  int lane = t & 63, wv = t >> 6;
  int wm = wv >> 2, wn = wv & 3;  // 2M x 4N
  int kq = lane >> 4, lr = lane & 15;

  // m204 bijective XCD swizzle: nwg=3126, q8=390, r8=6. mhalf pair (2p,2p+1)
  // contiguous on one XCD -> B panel L2 reuse across the pair.
  int bid = blockIdx.x;
  {
    int xcd = bid & 7, seq = bid >> 3;
    bid = (xcd < 6 ? xcd * 391 : 6 * 391 + (xcd - 6) * 390) + seq;
  }
  int pid = bid >> 1, mhalf = bid & 1;
  long c0 = (long)pid * 64;

  // B staging: thread owns column c (t&63), k-segment kseg (t>>6): 8 rows
  int c = t & 63, kseg = t >> 6;
  bool binb = (c0 + c) < C_N;
  const float* Bcol = Kg + c0 + c + (size_t)kseg * 8 * C_N;

  f32x4 acc[8] = {};
  float csq = 0.f;
  float bf0[8], bf1[8];  // B[j] lives in set (j&1)

  const unsigned char* wsTile = wsA + (size_t)mhalf * (8 * 32768);
  unsigned char* smemB = smem + 65536;
  unsigned char* browB = smemB + c * 128;

#define LOAD_B(dst, j)                                                       \
  {                                                                          \
    const float* src = Bcol + (size_t)((j) * 64) * C_N;                      \
    _Pragma("unroll") for (int i = 0; i < 8; ++i)                            \
        dst[i] = binb ? src[(size_t)i * C_N] : 0.f;                          \
  }

#define WRITE_B(src)                                                         \
  {                                                                          \
    _Pragma("unroll") for (int i = 0; i < 8; ++i) csq += src[i] * src[i];    \
    union { unsigned short u[8]; uint4 q; } pk;                              \
    _Pragma("unroll") for (int i = 0; i < 8; ++i) pk.u[i] = f2bf(src[i]);    \
    *(uint4*)(browB + ((kseg * 16) ^ ((c & 7) << 4))) = pk.q;                \
  }

  // ---- prologue: A[0] DMA -> buf0, B[0]/B[1] reg loads, B[0] -> LDS
  {
#pragma unroll
    for (int i = 0; i < 4; ++i) {
      int off = wv * 4096 + i * 1024;
      __builtin_amdgcn_global_load_lds((gptr_t)(wsTile + off + lane * 16),
                                       (sptr_t)(smem + off), 16, 0, 0);
    }
    __builtin_amdgcn_sched_barrier(0);
    LOAD_B(bf0, 0);
    __builtin_amdgcn_sched_barrier(0);
    LOAD_B(bf1, 1);
    __builtin_amdgcn_sched_barrier(0);
    asm volatile("s_waitcnt vmcnt(8)" ::: "memory");  // A[0]+B[0] done
    __builtin_amdgcn_sched_barrier(0);
    WRITE_B(bf0);
    __syncthreads();
  }

  // ---- main loop: 8 K-steps, fully unrolled (static reg-set selects)
#pragma unroll
  for (int kkt = 0; kkt < 8; ++kkt) {
    int cur = kkt & 1;
    if (kkt < 7) {
      // prefetch A[kkt+1] into the other buffer (DMA overlaps compute)
      const unsigned char* tA = wsTile + (size_t)(kkt + 1) * 32768;
#pragma unroll
      for (int i = 0; i < 4; ++i) {
        int off = wv * 4096 + i * 1024;
        __builtin_amdgcn_global_load_lds((gptr_t)(tA + off + lane * 16),
                                         (sptr_t)(smem + (cur ^ 1) * 32768 + off), 16, 0, 0);
      }
      __builtin_amdgcn_sched_barrier(0);
    }
    if (kkt < 6) {
      if (kkt & 1) { LOAD_B(bf1, kkt + 2); } else { LOAD_B(bf0, kkt + 2); }
      __builtin_amdgcn_sched_barrier(0);
    }

    // compute current buffers
    const unsigned char* Ab = smem + cur * 32768;
#pragma unroll
    for (int ks = 0; ks < 2; ++ks) {
      int kb = ks * 64 + kq * 16;
      int n = wn * 16 + lr;
      bf16x8 bfr = *(const bf16x8*)(smemB + n * 128 + (kb ^ ((n & 7) << 4)));
#pragma unroll
      for (int mf = 0; mf < 8; ++mf) {
        int m = wm * 128 + mf * 16 + lr;
        bf16x8 afr = *(const bf16x8*)(Ab + m * 128 + (kb ^ ((m & 7) << 4)));
        acc[mf] = __builtin_amdgcn_mfma_f32_16x16x32_bf16(afr, bfr, acc[mf], 0, 0, 0);
      }
    }

    // counted wait: retire {B[kkt+1] regs (8), A[kkt+1] DMA (4)}, keep
    // B[kkt+2] (8 newest) in flight across the barrier. Tail drains fully.
    if (kkt < 6) {
      asm volatile("s_waitcnt vmcnt(8)" ::: "memory");
    } else {
      asm volatile("s_waitcnt vmcnt(0)" ::: "memory");
    }
    __builtin_amdgcn_sched_barrier(0);
    __syncthreads();  // barrier-1: B-LDS reads done, A[kkt+1] landed

    if (kkt < 7) {
      if (kkt & 1) { WRITE_B(bf0); } else { WRITE_B(bf1); }
      __syncthreads();  // barrier-2: B[kkt+1] visible
    }
  }

  // ---- column norms + per-row params (B region dead)
  float* colpart = (float*)(smem + 65536);  // [8][64]
  float* invn    = (float*)(smem + 67584);  // [64]
  float* ctm_s   = (float*)(smem + 67840);  // [256]
  float* ftl_s   = (float*)(smem + 68864);  // [256]
  int*   lab_s   = (int*)  (smem + 69888);  // [256]
  colpart[t] = csq;
  if (t < 256) {
    ctm_s[t] = ctm_g[mhalf * 256 + t];
    ftl_s[t] = ftl_g[mhalf * 256 + t];
    lab_s[t] = label[mhalf * 256 + t];
  }
  __syncthreads();
  if (t < 64) {
    float s = 0.f;
#pragma unroll
    for (int g = 0; g < 8; ++g) s += colpart[g * 64 + t];
    invn[t] = 1.0f / sqrtf(fmaxf(s, 1e-30f));
  }
  __syncthreads();
  float tn = tnew_g[0];

  // ---- epilogue: 2 chunks of 128 rows; stage acc in LDS (aliases Abuf0,
  // barrier-separated from last compute on Abuf1), 256B-contiguous NT stores.
  for (int q = 0; q < 2; ++q) {
    if (wm == q) {
#pragma unroll
      for (int mf = 0; mf < 8; ++mf) {
#pragma unroll
        for (int j = 0; j < 4; ++j) {
          int row = mf * 16 + kq * 4 + j;  // [0,128)
          int col = wn * 16 + lr;          // [0,64)
          *(float*)(smem + row * 256 + ((col * 4) ^ (((row >> 2) & 3) << 6))) =
              acc[mf][j];
        }
      }
    }
    __syncthreads();
#pragma unroll
    for (int rr = 0; rr < 4; ++rr) {
      int row = rr * 32 + (t >> 4);   // [0,128)
      int cb = (t & 15) * 4;          // col base [0,64)
      f32x4 v = *(const f32x4*)(smem + row * 256 + ((cb * 4) ^ (((row >> 2) & 3) << 6)));
      long cgs = c0 + cb;
      if (cgs < C_N) {  // group fully valid (C_N % 4 == 0)
        int lrow = q * 128 + row;
        float cm = ctm_s[lrow], fl = ftl_s[lrow];
        int lb = lab_s[lrow];
        f32x4 iv = *(const f32x4*)(invn + cb);
        f32x4 o1v, o2v;
#pragma unroll
        for (int jj = 0; jj < 4; ++jj) {
          float cosv = fminf(1.f, fmaxf(-1.f, v[jj] * iv[jj]));
          o2v[jj] = cosv * S_SCALE;
          float ct = (cosv > cm) ? cosv * (tn + cosv) : cosv;
          if (lb == (int)(cgs + jj)) ct = fl;
          o1v[jj] = ct * S_SCALE;
        }
        size_t idx = (size_t)(mhalf * 256 + lrow) * C_N + cgs;
        __builtin_nontemporal_store(o1v, (f32x4*)(out1 + idx));
        __builtin_nontemporal_store(o2v, (f32x4*)(out2 + idx));
      }
    }
    __syncthreads();
  }
#undef LOAD_B
#undef WRITE_B
}

// ---------------------------------------------------------------------------
extern "C" void kernel_launch(void* const* d_in, const int* in_sizes, int n_in,
                              void* d_out, int out_size, void* d_ws, size_t ws_size,
                              hipStream_t stream)
{
  const float* emb   = (const float*)d_in[0];
  const float* Kg    = (const float*)d_in[1];
  const float* t_in  = (const float*)d_in[2];
  const int*   label = (const int*)d_in[3];

  float* out1 = (float*)d_out;                 // output * S   [512*100000]
  float* out2 = out1 + (size_t)B_M * C_N;      // origin * S   [512*100000]
  float* out3 = out1 + 2 * (size_t)B_M * C_N;  // scalar loss

  unsigned char* wsA = (unsigned char*)d_ws;   // 512KB swizzled bf16 A tiles
  float* tl   = (float*)((unsigned char*)d_ws + 524288);
  float* ctm  = tl + 512;
  float* ftl  = ctm + 512;
  float* tnew = ftl + 512;

  prep_kernel<<<512, 256, 0, stream>>>(emb, Kg, label, wsA, tl);
  finalize_kernel<<<1, 512, 0, stream>>>(tl, t_in, ctm, ftl, tnew, out3);
  int nb = 2 * 1563;  // BN=64 -> 1563 pids x 2 mhalf = 3126
  gemm_kernel<<<nb, 512, 0, stream>>>(Kg, wsA, ctm, ftl, label, tnew, out1, out2);
}